// Round 4
// baseline (182.157 us; speedup 1.0000x reference)
//
#include <hip/hip_runtime.h>
#include <hip/hip_bf16.h>

// ---------------------------------------------------------------------------
// Hierarchical_CBlock: 15 pairwise GEMMs [16384x512]@[512x256] + bias + tanh
// + NAS mask, then final GEMM [16384x3840]@[3840x256] + bias.
// Interfaces are fp32 (per reference dtypes); bf16 is used internally for
// MFMA (tolerance 2.31e-2 = bf16-grade). Masked pairs skipped entirely.
//   fast path: transpose+convert weights into d_ws (5.9 MB) + fused MFMA
//   safe path (ws too small): exact fp32 VALU fallback
// ---------------------------------------------------------------------------

typedef unsigned short u16;
typedef __bf16 bf16x8 __attribute__((ext_vector_type(8)));
typedef float f32x4 __attribute__((ext_vector_type(4)));
typedef float f32x8 __attribute__((ext_vector_type(8)));

#define BS 16384      // B*S tokens
#define EMB 256
#define PAIRS 15

__constant__ int c_pi[PAIRS] = {0,0,0,0,0,1,1,1,1,2,2,2,3,3,4};
__constant__ int c_pj[PAIRS] = {1,2,3,4,5,2,3,4,5,3,4,5,4,5,5};

__device__ __forceinline__ u16 f2bf_u(float x) {
    __bf16 b = (__bf16)x;   // RTN
    return __builtin_bit_cast(u16, b);
}

// ===================== transpose + fp32->bf16 convert ======================
// in: [P][R][C] fp32  ->  out: [P][C][R] bf16.  32x32 LDS tiles.
__global__ __launch_bounds__(256) void transpose_cvt(
    const float* __restrict__ in, u16* __restrict__ out, int R, int C)
{
    __shared__ float t[32][33];
    const int p  = blockIdx.z;
    const int r0 = blockIdx.x * 32;
    const int c0 = blockIdx.y * 32;
    const int tr = threadIdx.x >> 5;   // 0..7
    const int tc = threadIdx.x & 31;   // 0..31
    const float* ip = in + (size_t)p * R * C;
    u16* op = out + (size_t)p * C * R;
#pragma unroll
    for (int pass = 0; pass < 4; ++pass)
        t[pass * 8 + tr][tc] = ip[(size_t)(r0 + pass * 8 + tr) * C + c0 + tc];
    __syncthreads();
#pragma unroll
    for (int pass = 0; pass < 4; ++pass)
        op[(size_t)(c0 + pass * 8 + tr) * R + r0 + tc] =
            f2bf_u(t[tc][pass * 8 + tr]);
}

// ============================ fused MFMA path ==============================

// Stage a 32k x 256n bf16 tile (16 KB) into LDS as 1024 16B chunks,
// chunk index = kb*256 + n (kb = k-block of 8, n = column). Source rows are
// k-contiguous (transposed weights). global_load_lds: wave-uniform LDS base.
__device__ __forceinline__ void stage_tile(const u16* gsrc, int row_stride_us,
                                           int col_off_us, u16* lds_base, int tid) {
    int wave = tid >> 6;
#pragma unroll
    for (int r = 0; r < 2; ++r) {
        int c  = r * 512 + tid;
        int n  = c & 255;
        int kb = c >> 8;
        const u16* g = gsrc + (size_t)n * row_stride_us + col_off_us + kb * 8;
        u16* l = lds_base + (size_t)(r * 512 + wave * 64) * 8;  // wave-uniform
        __builtin_amdgcn_global_load_lds(
            (const __attribute__((address_space(1))) void*)g,
            (__attribute__((address_space(3))) void*)l,
            16, 0, 0);
    }
}

__global__ __launch_bounds__(512) void fused_cblock(
    const float* __restrict__ feats,   // [6][16384][256] fp32
    const u16* __restrict__ Wp_t,      // [15][256][512] bf16 (transposed)
    const float* __restrict__ b_pair,  // [15][256] fp32
    const u16* __restrict__ Wf_t,      // [256][3840] bf16 (transposed)
    const float* __restrict__ b_final, // [256] fp32
    const int* __restrict__ NAS,       // [6]
    float* __restrict__ out)           // [16384][256] fp32
{
    __shared__ u16 lds_b[2][8192];     // 2 x 16KB B-tile double buffer
    __shared__ u16 lds_h[64 * 264];    // h tile bf16, row stride 264 (pad 8)

    const int tid  = threadIdx.x;
    const int lane = tid & 63;
    const int wave = tid >> 6;
    const int wm   = wave & 3;         // 16-token slab
    const int wn   = wave >> 2;        // 128-col half
    const int quad = lane >> 4;
    const int l16  = lane & 15;
    const int t0   = blockIdx.x * 64;

    const f32x4 fzero = {0.f, 0.f, 0.f, 0.f};
    f32x4 acc2[8];
#pragma unroll
    for (int i = 0; i < 8; ++i) acc2[i] = fzero;

    int nasv[6];
#pragma unroll
    for (int f = 0; f < 6; ++f) nasv[f] = (f < 2) ? 1 : (NAS[f] != 0 ? 1 : 0);

    const int arow = t0 + wm * 16 + l16;   // token row for A-frags (m = l16)

    for (int p = 0; p < PAIRS; ++p) {
        const int fi = c_pi[p], fj = c_pj[p];
        if (!(nasv[fi] & nasv[fj])) continue;   // block-uniform skip

        const u16* WpT = Wp_t + (size_t)p * 256 * 512;

        // -------- GEMM1: h[64x256] = tanh(X[64x512] @ Wp + b) --------------
        f32x4 acc1[8];
#pragma unroll
        for (int i = 0; i < 8; ++i) acc1[i] = fzero;

        stage_tile(WpT, 512, 0, lds_b[0], tid);
        __syncthreads();
        for (int ks = 0; ks < 16; ++ks) {
            const int cur = ks & 1;
            if (ks < 15) stage_tile(WpT, 512, (ks + 1) * 32, lds_b[1 - cur], tid);
            // A frag: fp32 load + in-register cvt. k = ks*32 + quad*8 + j;
            // concat: ks<8 -> feature i embed (ks*32+..), ks>=8 -> feature j.
            const float* fsrc = feats + (size_t)((ks < 8) ? fi : fj) * BS * EMB;
            f32x8 af = *(const f32x8*)(fsrc + (size_t)arow * EMB +
                                       ((ks & 7) * 32) + quad * 8);
            bf16x8 a;
#pragma unroll
            for (int i = 0; i < 8; ++i) a[i] = (__bf16)af[i];
#pragma unroll
            for (int nt = 0; nt < 8; ++nt) {
                const int n = wn * 128 + nt * 16 + l16;
                bf16x8 b = *(const bf16x8*)(&lds_b[cur][(quad * 256 + n) * 8]);
                acc1[nt] = __builtin_amdgcn_mfma_f32_16x16x32_bf16(a, b, acc1[nt], 0, 0, 0);
            }
            __syncthreads();
        }

        // tanh + bias (fp32), h -> LDS bf16 (C-layout -> A-layout round trip)
#pragma unroll
        for (int nt = 0; nt < 8; ++nt) {
            const int n = wn * 128 + nt * 16 + l16;
            const float bias = b_pair[p * 256 + n];
#pragma unroll
            for (int r = 0; r < 4; ++r) {
                const int row = wm * 16 + quad * 4 + r;   // C/D: row=quad*4+reg
                lds_h[row * 264 + n] = f2bf_u(tanhf(acc1[nt][r] + bias));
            }
        }

        // -------- GEMM2: acc2 += h[64x256] @ Wf_p[256x256] ------------------
        stage_tile(Wf_t, 3840, p * 256, lds_b[0], tid);
        __syncthreads();   // also publishes lds_h
        for (int ks = 0; ks < 8; ++ks) {
            const int cur = ks & 1;
            if (ks < 7) stage_tile(Wf_t, 3840, p * 256 + (ks + 1) * 32, lds_b[1 - cur], tid);
            const int e0 = ks * 32 + quad * 8;
            const int row = wm * 16 + l16;
            bf16x8 a = *(const bf16x8*)(&lds_h[row * 264 + e0]);
#pragma unroll
            for (int nt = 0; nt < 8; ++nt) {
                const int n = wn * 128 + nt * 16 + l16;
                bf16x8 b = *(const bf16x8*)(&lds_b[cur][(quad * 256 + n) * 8]);
                acc2[nt] = __builtin_amdgcn_mfma_f32_16x16x32_bf16(a, b, acc2[nt], 0, 0, 0);
            }
            __syncthreads();
        }
    }

    // epilogue: + b_final, fp32 store
#pragma unroll
    for (int nt = 0; nt < 8; ++nt) {
        const int n = wn * 128 + nt * 16 + l16;
        const float bf = b_final[n];
#pragma unroll
        for (int r = 0; r < 4; ++r) {
            const int t = t0 + wm * 16 + quad * 4 + r;
            out[(size_t)t * EMB + n] = acc2[nt][r] + bf;
        }
    }
}

// ================== exact fp32 VALU fallback (ws-free) =====================

#define TOK 4

__global__ __launch_bounds__(256) void fallback_cblock(
    const float* __restrict__ feats, const float* __restrict__ W_pair,
    const float* __restrict__ b_pair, const float* __restrict__ W_final,
    const float* __restrict__ b_final, const int* __restrict__ NAS,
    float* __restrict__ out)
{
    __shared__ float xs[TOK][6 * 256];     // 24 KB
    __shared__ float hf[TOK][PAIRS * 256]; // 60 KB

    const int n  = threadIdx.x;
    const int t0 = blockIdx.x * TOK;

#pragma unroll
    for (int tk = 0; tk < TOK; ++tk)
#pragma unroll
        for (int f = 0; f < 6; ++f)
            xs[tk][f * 256 + n] = feats[((size_t)f * BS + t0 + tk) * EMB + n];
    __syncthreads();

    int nasv[6];
#pragma unroll
    for (int f = 0; f < 6; ++f) nasv[f] = (f < 2) ? 1 : (NAS[f] != 0 ? 1 : 0);

    for (int p = 0; p < PAIRS; ++p) {
        const int fi = c_pi[p], fj = c_pj[p];
        if (!(nasv[fi] & nasv[fj])) {
#pragma unroll
            for (int tk = 0; tk < TOK; ++tk) hf[tk][p * 256 + n] = 0.f;
            continue;
        }
        float acc[TOK];
        const float bias = b_pair[p * 256 + n];
#pragma unroll
        for (int tk = 0; tk < TOK; ++tk) acc[tk] = bias;
        const float* Wp = W_pair + (size_t)p * 512 * 256;
#pragma unroll 4
        for (int k = 0; k < 512; ++k) {
            const float w = Wp[(size_t)k * 256 + n];   // coalesced
            const int xoff = ((k < 256) ? fi : fj) * 256 + (k & 255);
#pragma unroll
            for (int tk = 0; tk < TOK; ++tk) acc[tk] += xs[tk][xoff] * w;
        }
#pragma unroll
        for (int tk = 0; tk < TOK; ++tk)
            hf[tk][p * 256 + n] = tanhf(acc[tk]);
    }
    __syncthreads();

    float acc[TOK];
    const float bf = b_final[n];
#pragma unroll
    for (int tk = 0; tk < TOK; ++tk) acc[tk] = bf;
#pragma unroll 4
    for (int k = 0; k < PAIRS * 256; ++k) {
        const float w = W_final[(size_t)k * 256 + n];  // coalesced
#pragma unroll
        for (int tk = 0; tk < TOK; ++tk) acc[tk] += hf[tk][k] * w;
    }
#pragma unroll
    for (int tk = 0; tk < TOK; ++tk)
        out[(size_t)(t0 + tk) * EMB + n] = acc[tk];
}

// ===========================================================================

extern "C" void kernel_launch(void* const* d_in, const int* in_sizes, int n_in,
                              void* d_out, int out_size, void* d_ws, size_t ws_size,
                              hipStream_t stream) {
    const float* feats   = (const float*)d_in[0];
    const float* W_pair  = (const float*)d_in[1];
    const float* b_pair  = (const float*)d_in[2];
    const float* W_final = (const float*)d_in[3];
    const float* b_final = (const float*)d_in[4];
    const int*   NAS     = (const int*)d_in[5];

    const size_t needed = ((size_t)PAIRS * 256 * 512 + (size_t)256 * 3840) * 2;

    if (ws_size >= needed) {
        u16* Wp_t = (u16*)d_ws;                         // 15*256*512 bf16
        u16* Wf_t = Wp_t + (size_t)PAIRS * 256 * 512;   // 256*3840 bf16
        transpose_cvt<<<dim3(512 / 32, 256 / 32, PAIRS), 256, 0, stream>>>(
            W_pair, Wp_t, 512, 256);
        transpose_cvt<<<dim3(3840 / 32, 256 / 32, 1), 256, 0, stream>>>(
            W_final, Wf_t, 3840, 256);
        fused_cblock<<<BS / 64, 512, 0, stream>>>(feats, Wp_t, b_pair, Wf_t,
                                                  b_final, NAS, (float*)d_out);
    } else {
        fallback_cblock<<<BS / TOK, 256, 0, stream>>>(feats, W_pair, b_pair,
                                                      W_final, b_final, NAS,
                                                      (float*)d_out);
    }
}